// Round 8
// baseline (277.003 us; speedup 1.0000x reference)
//
#include <hip/hip_runtime.h>
#include <math.h>
#include <stdint.h>

#define NUM_EMB 512
#define EMB_DIM 64
#define BB 16
#define TT 8192
#define BT (BB * TT)               // 131072 positions
#define NSPLIT 2                   // codebook split factor
#define KCHUNK (NUM_EMB / NSPLIT)  // 256 codewords per block

typedef float vf4  __attribute__((ext_vector_type(4)));
typedef float vf64 __attribute__((ext_vector_type(64)));

// ---------------------------------------------------------------------------
// Kernel 1: numpy-pairwise codebook norms C_k -> ws (scalar-loadable later).
// np.sum(row*row,-1), n=64: 8 stride-8 accumulators, ((r0+r1)+(r2+r3))+(...).
// ---------------------------------------------------------------------------
__global__ __launch_bounds__(256) void vq_norms(const float* __restrict__ cb,
                                                float* __restrict__ norms) {
  const int k = blockIdx.x * 256 + threadIdx.x;
  if (k >= NUM_EMB) return;
  const float* row = cb + k * EMB_DIM;
  float r[8];
#pragma unroll
  for (int j = 0; j < 8; ++j) r[j] = __fmul_rn(row[j], row[j]);
#pragma unroll
  for (int i = 8; i < 64; i += 8)
#pragma unroll
    for (int j = 0; j < 8; ++j)
      r[j] = __fadd_rn(r[j], __fmul_rn(row[i + j], row[i + j]));
  norms[k] = __fadd_rn(
      __fadd_rn(__fadd_rn(r[0], r[1]), __fadd_rn(r[2], r[3])),
      __fadd_rn(__fadd_rn(r[4], r[5]), __fadd_rn(r[6], r[7])));
}

// ---------------------------------------------------------------------------
// Kernel 2: half-codebook argmin. blockIdx = (pos_block << 1) | half.
// volatile x loads: the compiler may NOT rematerialize them inside the
// k-loop (r6/r7 showed VGPR=48/32 < the 64 regs xr needs -> it was
// re-loading x from L1 every iteration; that hidden VMEM stream was the
// stall). waves_per_eu(4,4) pins the allocator at the 128-VGPR budget so
// xr stays register-resident.
// Bit-exact numpy fp32 chains: sequential ascending-d acc=fl(acc+fl(x*c)),
// no fma; d_k = fl(fl(A - fl(2E)) + C_k); first-occurrence argmin.
// Result packed (float_bits(dmin)<<32)|k: u64 min == lexicographic min.
// ---------------------------------------------------------------------------
__global__ __launch_bounds__(256)
__attribute__((amdgpu_waves_per_eu(4, 4))) void vq_half(
    const float* __restrict__ x,
    const float* __restrict__ cb,
    const float* __restrict__ norms,
    uint64_t* __restrict__ cand) {
  const int tid   = threadIdx.x;
  const int half  = blockIdx.x & (NSPLIT - 1);
  const int p     = (blockIdx.x >> 1) * 256 + tid;   // position in [0, B*T)
  const int b     = p >> 13;
  const int t     = p & (TT - 1);
  const int kbase = half * KCHUNK;

  // ---- x[b,:,t] into registers; volatile forbids rematerialization ----
  vf64 xr;
  const volatile float* xb = x + (size_t)b * EMB_DIM * TT + t;
#pragma unroll
  for (int d = 0; d < 64; ++d) xr[d] = xb[(size_t)d * TT];

  // ---- A = numpy pairwise sum of squares ----
  float A;
  {
    float r[8];
#pragma unroll
    for (int j = 0; j < 8; ++j) r[j] = __fmul_rn(xr[j], xr[j]);
#pragma unroll
    for (int i = 8; i < 64; i += 8)
#pragma unroll
      for (int j = 0; j < 8; ++j)
        r[j] = __fadd_rn(r[j], __fmul_rn(xr[i + j], xr[i + j]));
    A = __fadd_rn(
        __fadd_rn(__fadd_rn(r[0], r[1]), __fadd_rn(r[2], r[3])),
        __fadd_rn(__fadd_rn(r[4], r[5]), __fadd_rn(r[6], r[7])));
  }

  float dmin = INFINITY;
  int best = kbase;

  // ---- 256 codewords, 2 rows/iter (keeps concurrent SGPR pressure low) ----
  const float* base = cb + (size_t)kbase * EMB_DIM;
  for (int kb = 0; kb < KCHUNK; kb += 2) {
    const vf4* r0 = (const vf4*)(base + (size_t)kb * EMB_DIM);
    const vf4* r1 = r0 + 16;
    float a0 = 0.f, a1 = 0.f;
#pragma unroll
    for (int d4 = 0; d4 < 16; ++d4) {
      vf4 c0 = r0[d4];
      vf4 c1 = r1[d4];
      const int d = d4 * 4;
      a0 = __fadd_rn(a0, __fmul_rn(xr[d + 0], c0.x));
      a0 = __fadd_rn(a0, __fmul_rn(xr[d + 1], c0.y));
      a0 = __fadd_rn(a0, __fmul_rn(xr[d + 2], c0.z));
      a0 = __fadd_rn(a0, __fmul_rn(xr[d + 3], c0.w));
      a1 = __fadd_rn(a1, __fmul_rn(xr[d + 0], c1.x));
      a1 = __fadd_rn(a1, __fmul_rn(xr[d + 1], c1.y));
      a1 = __fadd_rn(a1, __fmul_rn(xr[d + 2], c1.z));
      a1 = __fadd_rn(a1, __fmul_rn(xr[d + 3], c1.w));
    }
    const float2 nn = *(const float2*)(norms + kbase + kb);  // s_load_dwordx2
    float d0 = __fadd_rn(__fsub_rn(A, __fmul_rn(2.0f, a0)), nn.x);
    float d1 = __fadd_rn(__fsub_rn(A, __fmul_rn(2.0f, a1)), nn.y);
    if (d0 < dmin) { dmin = d0; best = kbase + kb; }
    if (d1 < dmin) { dmin = d1; best = kbase + kb + 1; }
  }

  // distances always > 0 (A ~ 64 dominates) -> float bits order-preserving.
  cand[(size_t)half * BT + p] =
      ((uint64_t)__float_as_uint(dmin) << 32) | (uint32_t)best;
}

// ---------------------------------------------------------------------------
// Kernel 3: combine the half-candidates (u64 min = dist-then-lowest-k),
// gather the winning row, write outputs with the reference's STE rounding:
//   out0 = fl(x + fl(q - x))   (quantized_st forward value)
//   out1 = q
// ---------------------------------------------------------------------------
__global__ __launch_bounds__(256) void vq_combine(
    const float* __restrict__ x,
    const float* __restrict__ cb,
    const uint64_t* __restrict__ cand,
    float* __restrict__ out) {
  const int p = blockIdx.x * 256 + threadIdx.x;
  const int b = p >> 13;
  const int t = p & (TT - 1);

  uint64_t m = cand[p];
  const uint64_t c1 = cand[(size_t)BT + p];
  if (c1 < m) m = c1;
  const int best = (int)(uint32_t)m;

  const vf4* qrow = (const vf4*)(cb + best * EMB_DIM);
  const float* xb = x + (size_t)b * EMB_DIM * TT + t;
  float* o0 = out + (size_t)b * EMB_DIM * TT + t;
  float* o1 = o0 + (size_t)BB * EMB_DIM * TT;
#pragma unroll
  for (int j = 0; j < 16; ++j) {
    vf4 q = qrow[j];
    size_t d0 = (size_t)(4 * j) * TT;
#pragma unroll
    for (int c = 0; c < 4; ++c) {
      size_t off = d0 + (size_t)c * TT;
      float qv = q[c];
      float xv = xb[off];
      // STE forward: fl(x + fl(q - x))
      o0[off] = __fadd_rn(xv, __fsub_rn(qv, xv));
      o1[off] = qv;
    }
  }
}

extern "C" void kernel_launch(void* const* d_in, const int* in_sizes, int n_in,
                              void* d_out, int out_size, void* d_ws, size_t ws_size,
                              hipStream_t stream) {
  const float* x  = (const float*)d_in[0];   // [16, 64, 8192]
  const float* cb = (const float*)d_in[1];   // [512, 64]
  float* out = (float*)d_out;                // 2 x [16, 64, 8192]

  uint64_t* cand  = (uint64_t*)d_ws;                           // 2*BT u64
  float*    norms = (float*)((char*)d_ws + (size_t)NSPLIT * BT * 8);  // 512 f32

  vq_norms<<<2, 256, 0, stream>>>(cb, norms);
  vq_half<<<(BT / 256) * NSPLIT, 256, 0, stream>>>(x, cb, norms, cand);
  vq_combine<<<BT / 256, 256, 0, stream>>>(x, cb, cand, out);
}

// Round 10
// 257.024 us; speedup vs baseline: 1.0777x; 1.0777x over previous
//
#include <hip/hip_runtime.h>
#include <math.h>
#include <stdint.h>

#define NUM_EMB 512
#define EMB_DIM 64
#define BB 16
#define TT 8192
#define BT (BB * TT)               // 131072 positions
#define NSPLIT 2                   // codebook split factor
#define KCHUNK (NUM_EMB / NSPLIT)  // 256 codewords per block

typedef float vf4 __attribute__((ext_vector_type(4)));

// ---------------------------------------------------------------------------
// Kernel 1: numpy-pairwise codebook norms C_k -> ws (scalar-loadable later).
// np.sum(row*row,-1), n=64: 8 stride-8 accumulators, ((r0+r1)+(r2+r3))+(...).
// ---------------------------------------------------------------------------
__global__ __launch_bounds__(256) void vq_norms(const float* __restrict__ cb,
                                                float* __restrict__ norms) {
  const int k = blockIdx.x * 256 + threadIdx.x;
  if (k >= NUM_EMB) return;
  const float* row = cb + k * EMB_DIM;
  float r[8];
#pragma unroll
  for (int j = 0; j < 8; ++j) r[j] = __fmul_rn(row[j], row[j]);
#pragma unroll
  for (int i = 8; i < 64; i += 8)
#pragma unroll
    for (int j = 0; j < 8; ++j)
      r[j] = __fadd_rn(r[j], __fmul_rn(row[i + j], row[i + j]));
  norms[k] = __fadd_rn(
      __fadd_rn(__fadd_rn(r[0], r[1]), __fadd_rn(r[2], r[3])),
      __fadd_rn(__fadd_rn(r[4], r[5]), __fadd_rn(r[6], r[7])));
}

// ---------------------------------------------------------------------------
// Kernel 2: half-codebook argmin. blockIdx = (pos_block << 1) | half.
// xr is pinned into VGPRs with an empty asm "+v" pass-through: the asm
// result is opaque, so the scheduler can neither SINK the x loads into the
// k-loop (r6/r7: VGPR=48/32, partial remat from L1 = the 22% stall) nor
// spill-and-reload legally cheaper than keeping the regs (budget=128 at
// 4 waves/SIMD, need ~95). Codebook via wave-uniform s_load (SMEM pipe).
// Bit-exact numpy fp32 chains: sequential ascending-d acc=fl(acc+fl(x*c)),
// no fma; d_k = fl(fl(A - fl(2E)) + C_k); first-occurrence argmin.
// Result packed (float_bits(dmin)<<32)|k: u64 min == lexicographic min.
// ---------------------------------------------------------------------------
__global__ __launch_bounds__(256, 4) void vq_half(
    const float* __restrict__ x,
    const float* __restrict__ cb,
    const float* __restrict__ norms,
    uint64_t* __restrict__ cand) {
  const int tid   = threadIdx.x;
  const int half  = blockIdx.x & (NSPLIT - 1);
  const int p     = (blockIdx.x >> 1) * 256 + tid;   // position in [0, B*T)
  const int b     = p >> 13;
  const int t     = p & (TT - 1);
  const int kbase = half * KCHUNK;

  // ---- x[b,:,t] into registers, then pin with opaque asm ----
  float xr[EMB_DIM];
  const float* xb = x + (size_t)b * EMB_DIM * TT + t;
#pragma unroll
  for (int d = 0; d < 64; ++d) xr[d] = xb[(size_t)d * TT];
#pragma unroll
  for (int d = 0; d < 64; ++d) asm volatile("" : "+v"(xr[d]));

  // ---- A = numpy pairwise sum of squares ----
  float A;
  {
    float r[8];
#pragma unroll
    for (int j = 0; j < 8; ++j) r[j] = __fmul_rn(xr[j], xr[j]);
#pragma unroll
    for (int i = 8; i < 64; i += 8)
#pragma unroll
      for (int j = 0; j < 8; ++j)
        r[j] = __fadd_rn(r[j], __fmul_rn(xr[i + j], xr[i + j]));
    A = __fadd_rn(
        __fadd_rn(__fadd_rn(r[0], r[1]), __fadd_rn(r[2], r[3])),
        __fadd_rn(__fadd_rn(r[4], r[5]), __fadd_rn(r[6], r[7])));
  }

  float dmin = INFINITY;
  int best = kbase;

  // ---- 256 codewords, 2 rows/iter (keeps concurrent SGPR pressure low) ----
  const float* base = cb + (size_t)kbase * EMB_DIM;
  for (int kb = 0; kb < KCHUNK; kb += 2) {
    const vf4* r0 = (const vf4*)(base + (size_t)kb * EMB_DIM);
    const vf4* r1 = r0 + 16;
    float a0 = 0.f, a1 = 0.f;
#pragma unroll
    for (int d4 = 0; d4 < 16; ++d4) {
      vf4 c0 = r0[d4];
      vf4 c1 = r1[d4];
      const int d = d4 * 4;
      a0 = __fadd_rn(a0, __fmul_rn(xr[d + 0], c0.x));
      a0 = __fadd_rn(a0, __fmul_rn(xr[d + 1], c0.y));
      a0 = __fadd_rn(a0, __fmul_rn(xr[d + 2], c0.z));
      a0 = __fadd_rn(a0, __fmul_rn(xr[d + 3], c0.w));
      a1 = __fadd_rn(a1, __fmul_rn(xr[d + 0], c1.x));
      a1 = __fadd_rn(a1, __fmul_rn(xr[d + 1], c1.y));
      a1 = __fadd_rn(a1, __fmul_rn(xr[d + 2], c1.z));
      a1 = __fadd_rn(a1, __fmul_rn(xr[d + 3], c1.w));
    }
    const float2 nn = *(const float2*)(norms + kbase + kb);  // s_load_dwordx2
    float d0 = __fadd_rn(__fsub_rn(A, __fmul_rn(2.0f, a0)), nn.x);
    float d1 = __fadd_rn(__fsub_rn(A, __fmul_rn(2.0f, a1)), nn.y);
    if (d0 < dmin) { dmin = d0; best = kbase + kb; }
    if (d1 < dmin) { dmin = d1; best = kbase + kb + 1; }
  }

  // distances always > 0 (A ~ 64 dominates) -> float bits order-preserving.
  cand[(size_t)half * BT + p] =
      ((uint64_t)__float_as_uint(dmin) << 32) | (uint32_t)best;
}

// ---------------------------------------------------------------------------
// Kernel 3: combine the half-candidates (u64 min = dist-then-lowest-k),
// gather the winning row, write outputs with the reference's STE rounding:
//   out0 = fl(x + fl(q - x))   (quantized_st forward value)
//   out1 = q
// ---------------------------------------------------------------------------
__global__ __launch_bounds__(256) void vq_combine(
    const float* __restrict__ x,
    const float* __restrict__ cb,
    const uint64_t* __restrict__ cand,
    float* __restrict__ out) {
  const int p = blockIdx.x * 256 + threadIdx.x;
  const int b = p >> 13;
  const int t = p & (TT - 1);

  uint64_t m = cand[p];
  const uint64_t c1 = cand[(size_t)BT + p];
  if (c1 < m) m = c1;
  const int best = (int)(uint32_t)m;

  const vf4* qrow = (const vf4*)(cb + best * EMB_DIM);
  const float* xb = x + (size_t)b * EMB_DIM * TT + t;
  float* o0 = out + (size_t)b * EMB_DIM * TT + t;
  float* o1 = o0 + (size_t)BB * EMB_DIM * TT;
#pragma unroll
  for (int j = 0; j < 16; ++j) {
    vf4 q = qrow[j];
    size_t d0 = (size_t)(4 * j) * TT;
#pragma unroll
    for (int c = 0; c < 4; ++c) {
      size_t off = d0 + (size_t)c * TT;
      float qv = q[c];
      float xv = xb[off];
      // STE forward: fl(x + fl(q - x))
      o0[off] = __fadd_rn(xv, __fsub_rn(qv, xv));
      o1[off] = qv;
    }
  }
}

extern "C" void kernel_launch(void* const* d_in, const int* in_sizes, int n_in,
                              void* d_out, int out_size, void* d_ws, size_t ws_size,
                              hipStream_t stream) {
  const float* x  = (const float*)d_in[0];   // [16, 64, 8192]
  const float* cb = (const float*)d_in[1];   // [512, 64]
  float* out = (float*)d_out;                // 2 x [16, 64, 8192]

  uint64_t* cand  = (uint64_t*)d_ws;                           // 2*BT u64
  float*    norms = (float*)((char*)d_ws + (size_t)NSPLIT * BT * 8);  // 512 f32

  vq_norms<<<2, 256, 0, stream>>>(cb, norms);
  vq_half<<<(BT / 256) * NSPLIT, 256, 0, stream>>>(x, cb, norms, cand);
  vq_combine<<<BT / 256, 256, 0, stream>>>(x, cb, cand, out);
}